// Round 6
// baseline (332.453 us; speedup 1.0000x reference)
//
#include <hip/hip_runtime.h>
#include <cstdint>

#define N_NODES 50000
#define N_EDGES 800000
#define C 64
#define N_PAD 50176                 // 196 * 256
#define SCAN_BLOCKS 196
#define HIST_CHUNKS 96              // 96 chunks x 8334 edges >= E
#define CHUNK_SZ 8334

typedef __attribute__((ext_vector_type(8))) short bf16x8;   // 8 bf16 in 4 VGPRs
typedef __attribute__((ext_vector_type(4))) float f32x4;

// ---------------- workspace layout (float/word units) ----------------
static constexpr size_t OFF_CNT  = 0;                        // N_PAD ints (count -> cursor)
static constexpr size_t OFF_DEG  = 50176;                    // N_PAD floats (zeroed w/ cnt)
static constexpr size_t OFF_PART = 100352;                   // 256 ints
static constexpr size_t OFF_POFF = 100608;                   // 256 ints
static constexpr size_t OFF_DINV = 100864;                   // N floats
static constexpr size_t OFF_CSR  = 151040;                   // E int2 (byte off %8 == 0)
static constexpr size_t OFF_BZR  = OFF_CSR + 2 * (size_t)N_EDGES;   // 1,751,040: 16384 fl
static constexpr size_t OFF_BH   = OFF_BZR + 16384;                 // 8192 fl
static constexpr size_t OFF_PX   = OFF_BH + 8192;                   // 1,775,616: N*C fl
static constexpr size_t OFF_PH   = OFF_PX + (size_t)N_NODES * C;    // N*C fl (later Prh)
static constexpr size_t OFF_XH   = OFF_PH + (size_t)N_NODES * C;    // N*C uints
static constexpr size_t OFF_RH   = OFF_XH + (size_t)N_NODES * C;    // N*C fl
static constexpr size_t OFF_RHD  = OFF_RH + (size_t)N_NODES * C;    // N*C ushort
// total = 15,375,616 words = 61.5 MB (round-5 used 64.5 MB OK)

__device__ __forceinline__ short f2bf(float f) {             // RNE fp32 -> bf16
    unsigned u = __float_as_uint(f);
    u += 0x7fffu + ((u >> 16) & 1u);
    return (short)(u >> 16);
}
__device__ __forceinline__ float bf_lo(unsigned v) { return __uint_as_float(v << 16); }
__device__ __forceinline__ float bf_hi(unsigned v) { return __uint_as_float(v & 0xffff0000u); }
__device__ __forceinline__ float fast_sigmoid(float v) { return 1.f / (1.f + __expf(-v)); }
__device__ __forceinline__ float fast_tanh(float v) { return 1.f - 2.f / (__expf(2.f * v) + 1.f); }

// ======================= zero (cnt+deg) + weight pack, fused =======================
// blocks [0,98): zero 100352 words (cnt ints + deg floats) as int4.
// blocks [98,122): pack Wz|Wr -> Bzr, Wh -> Bh in MFMA B-fragment order.
__global__ __launch_bounds__(256) void zero_pack_kernel(
        int* __restrict__ zdst,
        const float* __restrict__ Wz, const float* __restrict__ Wr,
        const float* __restrict__ Wh,
        short* __restrict__ Bzr, short* __restrict__ Bh) {
    if (blockIdx.x < 98) {
        int i = blockIdx.x * 256 + threadIdx.x;   // < 25088 int4s
        ((int4*)zdst)[i] = make_int4(0, 0, 0, 0);
        return;
    }
    int gid = (blockIdx.x - 98) * 256 + threadIdx.x;   // < 6144
    if (gid < 4096) {                                   // zr: 64 (kt,ct) x 64 lanes
        int ktct = gid >> 6, lane = gid & 63;
        int kt = ktct >> 3, ct = ktct & 7;
        int colg = ct * 16 + (lane & 15);
        int k0 = kt * 32 + (lane >> 4) * 8;
        const float* W = (colg < 64) ? Wz : Wr;
        int c = colg & 63;
        short v[8];
        #pragma unroll
        for (int j = 0; j < 8; ++j) {
            int k = k0 + j;
            v[j] = f2bf(W[(k >> 7) * (128 * 64) + (k & 127) * 64 + c]);
        }
        *(bf16x8*)(Bzr + (size_t)ktct * 512 + lane * 8) = *(bf16x8*)v;
    } else {                                            // h: 32 (kt,ct) x 64 lanes
        int idx = gid - 4096;
        int ktct = idx >> 6, lane = idx & 63;
        int kt = ktct >> 2, ct = ktct & 3;
        int colg = ct * 16 + (lane & 15);
        int k0 = kt * 32 + (lane >> 4) * 8;
        short v[8];
        #pragma unroll
        for (int j = 0; j < 8; ++j) {
            int k = k0 + j;
            v[j] = f2bf(Wh[(k >> 7) * (128 * 64) + (k & 127) * 64 + colg]);
        }
        *(bf16x8*)(Bh + (size_t)ktct * 512 + lane * 8) = *(bf16x8*)v;
    }
}

// ======================= XCD-partitioned histogram + degree =======================
// grid = 8 partitions x HIST_CHUNKS. part = blockIdx & 7 -> XCD via %8 round-robin
// (locality heuristic only; the partition predicate is consistent across blocks,
//  so each edge is processed exactly once regardless of the actual mapping).
__global__ __launch_bounds__(256) void hist_deg_kernel(
        const int* __restrict__ row, const float* __restrict__ w,
        int* __restrict__ cnt, float* __restrict__ deg) {
    int part = blockIdx.x & 7;
    int chunk = blockIdx.x >> 3;
    int e0 = chunk * CHUNK_SZ;
    int e1 = min(e0 + CHUNK_SZ, N_EDGES);
    for (int e = e0 + (int)threadIdx.x; e < e1; e += 256) {
        int r = row[e];
        if (r / 6250 == part) {
            atomicAdd(&cnt[r], 1);
            atomicAdd(&deg[r], w[e]);
        }
    }
}

// ======================= scan (cnt -> exclusive prefix = cursor) ==================
__global__ __launch_bounds__(256) void scan_part_kernel(const int* __restrict__ cnt,
                                                        int* __restrict__ part) {
    __shared__ int s[256];
    int t = threadIdx.x;
    s[t] = cnt[blockIdx.x * 256 + t];
    __syncthreads();
    for (int d = 128; d > 0; d >>= 1) {
        if (t < d) s[t] += s[t + d];
        __syncthreads();
    }
    if (t == 0) part[blockIdx.x] = s[0];
}

__global__ __launch_bounds__(256) void scan_root_kernel(const int* __restrict__ part,
                                                        int* __restrict__ poff) {
    __shared__ int s[256];
    int t = threadIdx.x;
    int v = (t < SCAN_BLOCKS) ? part[t] : 0;
    s[t] = v;
    __syncthreads();
    for (int d = 1; d < 256; d <<= 1) {
        int add = (t >= d) ? s[t - d] : 0;
        __syncthreads();
        s[t] += add;
        __syncthreads();
    }
    if (t < SCAN_BLOCKS) poff[t] = s[t] - v;
}

__global__ __launch_bounds__(256) void scan_add_kernel(const int* __restrict__ cnt,
                                                       const int* __restrict__ poff,
                                                       int* __restrict__ cursor) {
    __shared__ int s[256];
    int t = threadIdx.x;
    int i = blockIdx.x * 256 + t;
    int v = cnt[i];
    s[t] = v;
    __syncthreads();
    for (int d = 1; d < 256; d <<= 1) {
        int add = (t >= d) ? s[t - d] : 0;
        __syncthreads();
        s[t] += add;
        __syncthreads();
    }
    cursor[i] = s[t] - v + poff[blockIdx.x];
}

// ======================= XCD-partitioned scatter into CSR =========================
// after this, cursor[n] == rowptr[n+1]. Each partition's ~800KB CSR slice is
// written by one XCD -> full-line coalescing in its L2 (target: WRITE 52->~8 MB).
__global__ __launch_bounds__(256) void scatter_kernel(
        const int* __restrict__ row, const int* __restrict__ col,
        const float* __restrict__ w,
        int* __restrict__ cursor, int2* __restrict__ csr) {
    int part = blockIdx.x & 7;
    int chunk = blockIdx.x >> 3;
    int e0 = chunk * CHUNK_SZ;
    int e1 = min(e0 + CHUNK_SZ, N_EDGES);
    for (int e = e0 + (int)threadIdx.x; e < e1; e += 256) {
        int r = row[e];
        if (r / 6250 == part) {
            int pos = atomicAdd(&cursor[r], 1);
            csr[pos] = make_int2(col[e], __float_as_int(w[e]));
        }
    }
}

// ======================= dinv + xh pack, fused =======================
// xh[n*64+c] = (bf16(h*dinv) << 16) | bf16(x*dinv); dinv[n] stored for later.
__global__ __launch_bounds__(256) void dinv_xh_kernel(
        const float* __restrict__ x, const float* __restrict__ h,
        const float* __restrict__ deg,
        float* __restrict__ dinv, unsigned* __restrict__ xh) {
    int i = blockIdx.x * 256 + threadIdx.x;   // exactly N*16 = 800000 threads
    int n = i >> 4;
    float dg = deg[n];
    float d = (dg > 0.f) ? rsqrtf(dg) : 0.f;
    if ((i & 15) == 0) dinv[n] = d;
    float4 xv = ((const float4*)x)[i];
    float4 hv = ((const float4*)h)[i];
    uint4 o;
    o.x = ((unsigned)(unsigned short)f2bf(hv.x * d) << 16) | (unsigned short)f2bf(xv.x * d);
    o.y = ((unsigned)(unsigned short)f2bf(hv.y * d) << 16) | (unsigned short)f2bf(xv.y * d);
    o.z = ((unsigned)(unsigned short)f2bf(hv.z * d) << 16) | (unsigned short)f2bf(xv.z * d);
    o.w = ((unsigned)(unsigned short)f2bf(hv.w * d) << 16) | (unsigned short)f2bf(xv.w * d);
    ((uint4*)xh)[i] = o;
}

// ======================= propagation (pull, CSR) =======================
__global__ __launch_bounds__(256) void prop2_gather_kernel(
        const int* __restrict__ cursor, const int2* __restrict__ csr,
        const float* __restrict__ dinv, const unsigned* __restrict__ xh,
        float* __restrict__ Px, float* __restrict__ Ph) {
    int n = (blockIdx.x * 256 + threadIdx.x) >> 6;
    int lane = threadIdx.x & 63;
    if (n >= N_NODES) return;
    int start = (n == 0) ? 0 : cursor[n - 1];
    int end = cursor[n];
    float ax = 0.f, ah = 0.f;
    int e = start;
    for (; e + 4 <= end; e += 4) {
        int2 c0 = csr[e], c1 = csr[e + 1], c2 = csr[e + 2], c3 = csr[e + 3];
        unsigned v0 = xh[c0.x * C + lane];
        unsigned v1 = xh[c1.x * C + lane];
        unsigned v2 = xh[c2.x * C + lane];
        unsigned v3 = xh[c3.x * C + lane];
        float w0 = __int_as_float(c0.y), w1 = __int_as_float(c1.y);
        float w2 = __int_as_float(c2.y), w3 = __int_as_float(c3.y);
        ax = fmaf(w0, bf_lo(v0), ax);  ah = fmaf(w0, bf_hi(v0), ah);
        ax = fmaf(w1, bf_lo(v1), ax);  ah = fmaf(w1, bf_hi(v1), ah);
        ax = fmaf(w2, bf_lo(v2), ax);  ah = fmaf(w2, bf_hi(v2), ah);
        ax = fmaf(w3, bf_lo(v3), ax);  ah = fmaf(w3, bf_hi(v3), ah);
    }
    for (; e < end; ++e) {
        int2 cw = csr[e];
        unsigned v = xh[cw.x * C + lane];
        float wv = __int_as_float(cw.y);
        ax = fmaf(wv, bf_lo(v), ax);
        ah = fmaf(wv, bf_hi(v), ah);
    }
    float s = -dinv[n];
    Px[n * C + lane] = s * ax;
    Ph[n * C + lane] = s * ah;
}

__global__ __launch_bounds__(256) void prop1_gather_kernel(
        const int* __restrict__ cursor, const int2* __restrict__ csr,
        const float* __restrict__ dinv,
        const unsigned short* __restrict__ rhd, float* __restrict__ Prh) {
    int n = (blockIdx.x * 256 + threadIdx.x) >> 6;
    int lane = threadIdx.x & 63;
    if (n >= N_NODES) return;
    int start = (n == 0) ? 0 : cursor[n - 1];
    int end = cursor[n];
    float acc = 0.f;
    int e = start;
    for (; e + 4 <= end; e += 4) {
        int2 c0 = csr[e], c1 = csr[e + 1], c2 = csr[e + 2], c3 = csr[e + 3];
        float v0 = __uint_as_float((unsigned)rhd[c0.x * C + lane] << 16);
        float v1 = __uint_as_float((unsigned)rhd[c1.x * C + lane] << 16);
        float v2 = __uint_as_float((unsigned)rhd[c2.x * C + lane] << 16);
        float v3 = __uint_as_float((unsigned)rhd[c3.x * C + lane] << 16);
        acc = fmaf(__int_as_float(c0.y), v0, acc);
        acc = fmaf(__int_as_float(c1.y), v1, acc);
        acc = fmaf(__int_as_float(c2.y), v2, acc);
        acc = fmaf(__int_as_float(c3.y), v3, acc);
    }
    for (; e < end; ++e) {
        int2 cw = csr[e];
        float v = __uint_as_float((unsigned)rhd[cw.x * C + lane] << 16);
        acc = fmaf(__int_as_float(cw.y), v, acc);
    }
    Prh[n * C + lane] = -dinv[n] * acc;
}

// ======================= dense GEMMs (MFMA bf16) =======================
// One wave = 16 nodes x 128 cols (zr). A = [x|h|Px|Ph].
// A-frag: A[m=lane&15][k = kt*32 + (lane>>4)*8 + j].  C/D: col=lane&15, row=(lane>>4)*4+reg.
__global__ __launch_bounds__(256) void gemm_zr_mfma_kernel(
        const float* __restrict__ x,  const float* __restrict__ h,
        const float* __restrict__ Px, const float* __restrict__ Ph,
        const short* __restrict__ Bzr,
        const float* __restrict__ bz, const float* __restrict__ br,
        const float* __restrict__ dinv,
        float* __restrict__ z, float* __restrict__ rh, unsigned short* __restrict__ rhd) {
    int wave = (blockIdx.x * 256 + threadIdx.x) >> 6;
    int lane = threadIdx.x & 63;
    int node0 = wave * 16;
    if (node0 >= N_NODES) return;
    int rowA = lane & 15, q = lane >> 4;
    int nodeA = node0 + rowA;

    f32x4 acc[8];
    #pragma unroll
    for (int i = 0; i < 8; ++i) acc[i] = (f32x4){0.f, 0.f, 0.f, 0.f};

    const bf16x8* Bp = (const bf16x8*)Bzr;
    #pragma unroll
    for (int kt = 0; kt < 8; ++kt) {
        const float* src = (kt < 2) ? x : (kt < 4) ? h : (kt < 6) ? Px : Ph;
        const float* p = src + (size_t)nodeA * C + (kt & 1) * 32 + q * 8;
        float4 f0 = *(const float4*)p;
        float4 f1 = *(const float4*)(p + 4);
        short av[8] = {f2bf(f0.x), f2bf(f0.y), f2bf(f0.z), f2bf(f0.w),
                       f2bf(f1.x), f2bf(f1.y), f2bf(f1.z), f2bf(f1.w)};
        bf16x8 a = *(bf16x8*)av;
        #pragma unroll
        for (int ct = 0; ct < 8; ++ct) {
            bf16x8 b = Bp[(kt * 8 + ct) * 64 + lane];
            acc[ct] = __builtin_amdgcn_mfma_f32_16x16x32_bf16(a, b, acc[ct], 0, 0, 0);
        }
    }

    float dv[4];
    #pragma unroll
    for (int r = 0; r < 4; ++r) dv[r] = dinv[node0 + q * 4 + r];

    #pragma unroll
    for (int ct = 0; ct < 8; ++ct) {
        int colg = ct * 16 + (lane & 15);
        if (ct < 4) {                       // z columns
            float bias = bz[colg];
            #pragma unroll
            for (int r = 0; r < 4; ++r) {
                int node = node0 + q * 4 + r;
                z[(size_t)node * C + colg] = fast_sigmoid(acc[ct][r] + bias);
            }
        } else {                            // r columns -> rh (fp32), rhd (bf16)
            int oc = colg - 64;
            float bias = br[oc];
            #pragma unroll
            for (int r = 0; r < 4; ++r) {
                int node = node0 + q * 4 + r;
                float sg = fast_sigmoid(acc[ct][r] + bias);
                float rhv = sg * h[(size_t)node * C + oc];
                rh [(size_t)node * C + oc] = rhv;
                rhd[(size_t)node * C + oc] = (unsigned short)f2bf(rhv * dv[r]);
            }
        }
    }
}

// One wave = 16 nodes x 64 cols. A = [x|rh|Px|Prh]. out = (1-z)*h + z*tanh(pre)
__global__ __launch_bounds__(256) void gemm_h_mfma_kernel(
        const float* __restrict__ x,  const float* __restrict__ rh,
        const float* __restrict__ Px, const float* __restrict__ Prh,
        const short* __restrict__ Bh, const float* __restrict__ bh,
        const float* __restrict__ z,  const float* __restrict__ h,
        float* __restrict__ out) {
    int wave = (blockIdx.x * 256 + threadIdx.x) >> 6;
    int lane = threadIdx.x & 63;
    int node0 = wave * 16;
    if (node0 >= N_NODES) return;
    int rowA = lane & 15, q = lane >> 4;
    int nodeA = node0 + rowA;

    f32x4 acc[4];
    #pragma unroll
    for (int i = 0; i < 4; ++i) acc[i] = (f32x4){0.f, 0.f, 0.f, 0.f};

    const bf16x8* Bp = (const bf16x8*)Bh;
    #pragma unroll
    for (int kt = 0; kt < 8; ++kt) {
        const float* src = (kt < 2) ? x : (kt < 4) ? rh : (kt < 6) ? Px : Prh;
        const float* p = src + (size_t)nodeA * C + (kt & 1) * 32 + q * 8;
        float4 f0 = *(const float4*)p;
        float4 f1 = *(const float4*)(p + 4);
        short av[8] = {f2bf(f0.x), f2bf(f0.y), f2bf(f0.z), f2bf(f0.w),
                       f2bf(f1.x), f2bf(f1.y), f2bf(f1.z), f2bf(f1.w)};
        bf16x8 a = *(bf16x8*)av;
        #pragma unroll
        for (int ct = 0; ct < 4; ++ct) {
            bf16x8 b = Bp[(kt * 4 + ct) * 64 + lane];
            acc[ct] = __builtin_amdgcn_mfma_f32_16x16x32_bf16(a, b, acc[ct], 0, 0, 0);
        }
    }

    #pragma unroll
    for (int ct = 0; ct < 4; ++ct) {
        int oc = ct * 16 + (lane & 15);
        float bias = bh[oc];
        #pragma unroll
        for (int r = 0; r < 4; ++r) {
            int node = node0 + q * 4 + r;
            float ht = fast_tanh(acc[ct][r] + bias);
            float zz = z[(size_t)node * C + oc];
            float hv = h[(size_t)node * C + oc];
            out[(size_t)node * C + oc] = (1.f - zz) * hv + zz * ht;
        }
    }
}

extern "C" void kernel_launch(void* const* d_in, const int* in_sizes, int n_in,
                              void* d_out, int out_size, void* d_ws, size_t ws_size,
                              hipStream_t stream) {
    const float* x    = (const float*)d_in[0];
    const int*   eidx = (const int*)  d_in[1];
    const float* w    = (const float*)d_in[2];
    const float* h    = (const float*)d_in[3];
    const float* Wz   = (const float*)d_in[4];
    const float* bz   = (const float*)d_in[5];
    const float* Wr   = (const float*)d_in[6];
    const float* br   = (const float*)d_in[7];
    const float* Wh   = (const float*)d_in[8];
    const float* bh   = (const float*)d_in[9];
    float* out = (float*)d_out;
    float* ws  = (float*)d_ws;

    const int* row = eidx;
    const int* col = eidx + N_EDGES;

    int*            cnt  = (int*)(ws + OFF_CNT);      // becomes cursor / rowptr+1
    float*          deg  = ws + OFF_DEG;
    int*            part = (int*)(ws + OFF_PART);
    int*            poff = (int*)(ws + OFF_POFF);
    float*          dinv = ws + OFF_DINV;
    int2*           csr  = (int2*)(ws + OFF_CSR);
    short*          Bzr  = (short*)(ws + OFF_BZR);
    short*          Bh   = (short*)(ws + OFF_BH);
    float*          Px   = ws + OFF_PX;
    float*          Ph   = ws + OFF_PH;               // later Prh
    unsigned*       xh   = (unsigned*)(ws + OFF_XH);
    float*          rh   = ws + OFF_RH;
    unsigned short* rhd  = (unsigned short*)(ws + OFF_RHD);
    float*          z    = out;                       // z lives in d_out until gemm_h

    // ---- zero cnt+deg, pack weights (fused) ----
    zero_pack_kernel<<<98 + 24, 256, 0, stream>>>((int*)ws, Wz, Wr, Wh, Bzr, Bh);

    // ---- histogram + degree (XCD-partitioned) ----
    hist_deg_kernel<<<8 * HIST_CHUNKS, 256, 0, stream>>>(row, w, cnt, deg);

    // ---- exclusive scan -> cursor ----
    scan_part_kernel<<<SCAN_BLOCKS, 256, 0, stream>>>(cnt, part);
    scan_root_kernel<<<1, 256, 0, stream>>>(part, poff);
    scan_add_kernel<<<SCAN_BLOCKS, 256, 0, stream>>>(cnt, poff, cnt);

    // ---- scatter into CSR (XCD-partitioned) ----
    scatter_kernel<<<8 * HIST_CHUNKS, 256, 0, stream>>>(row, col, w, cnt, csr);

    // ---- dinv + packed bf16 features ----
    dinv_xh_kernel<<<(N_NODES * 16) / 256, 256, 0, stream>>>(x, h, deg, dinv, xh);

    // ---- Px = Lhat@x, Ph = Lhat@h ----
    prop2_gather_kernel<<<(N_NODES * 64 + 255) / 256, 256, 0, stream>>>(
        cnt, csr, dinv, xh, Px, Ph);

    // ---- z, rh, rhd ----
    {
        int waves = (N_NODES + 15) / 16;          // 3125
        int blocks = (waves + 3) / 4;             // 782
        gemm_zr_mfma_kernel<<<blocks, 256, 0, stream>>>(
            x, h, Px, Ph, Bzr, bz, br, dinv, z, rh, rhd);
    }

    // ---- Prh = Lhat@(r*h) (into Ph slot) ----
    prop1_gather_kernel<<<(N_NODES * 64 + 255) / 256, 256, 0, stream>>>(
        cnt, csr, dinv, rhd, Ph);

    // ---- candidate + GRU blend ----
    {
        int waves = (N_NODES + 15) / 16;
        int blocks = (waves + 3) / 4;
        gemm_h_mfma_kernel<<<blocks, 256, 0, stream>>>(
            x, rh, Px, Ph, Bh, bh, z, h, out);
    }
}

// Round 7
// 298.526 us; speedup vs baseline: 1.1136x; 1.1136x over previous
//
#include <hip/hip_runtime.h>
#include <cstdint>

#define N_NODES 50000
#define N_EDGES 800000
#define C 64
#define N_PAD 50176                 // 196 * 256
#define SCAN_BLOCKS 196
#define HIST_CHUNKS 96              // for partitioned scatter: 96 chunks x 8334 >= E
#define CHUNK_SZ 8334

typedef __attribute__((ext_vector_type(8))) short bf16x8;   // 8 bf16 in 4 VGPRs
typedef __attribute__((ext_vector_type(4))) float f32x4;

// ---------------- workspace layout (float/word units) ----------------
static constexpr size_t OFF_CNT  = 0;                        // N_PAD ints (count -> cursor)
static constexpr size_t OFF_PART = 100352;                   // 256 ints
static constexpr size_t OFF_POFF = 100608;                   // 256 ints
static constexpr size_t OFF_DINV = 100864;                   // N floats
static constexpr size_t OFF_CSR  = 151040;                   // E int2
static constexpr size_t OFF_BZR  = OFF_CSR + 2 * (size_t)N_EDGES;   // 16384 fl
static constexpr size_t OFF_BH   = OFF_BZR + 16384;                 // 8192 fl
static constexpr size_t OFF_PX   = OFF_BH + 8192;                   // N*C fl
static constexpr size_t OFF_PH   = OFF_PX + (size_t)N_NODES * C;    // N*C fl (later Prh)
static constexpr size_t OFF_XH   = OFF_PH + (size_t)N_NODES * C;    // N*C uints
static constexpr size_t OFF_RH   = OFF_XH + (size_t)N_NODES * C;    // N*C fl
static constexpr size_t OFF_RHD  = OFF_RH + (size_t)N_NODES * C;    // N*C ushort
// total ~61.5 MB (proven OK)

__device__ __forceinline__ short f2bf(float f) {             // RNE fp32 -> bf16
    unsigned u = __float_as_uint(f);
    u += 0x7fffu + ((u >> 16) & 1u);
    return (short)(u >> 16);
}
__device__ __forceinline__ float bf_lo(unsigned v) { return __uint_as_float(v << 16); }
__device__ __forceinline__ float bf_hi(unsigned v) { return __uint_as_float(v & 0xffff0000u); }
__device__ __forceinline__ float fast_sigmoid(float v) { return 1.f / (1.f + __expf(-v)); }
__device__ __forceinline__ float fast_tanh(float v) { return 1.f - 2.f / (__expf(2.f * v) + 1.f); }

// ======================= zero cnt + weight pack, fused =======================
// blocks [0,49): zero 50176 ints (cnt) as int4. blocks [49,73): pack weights.
__global__ __launch_bounds__(256) void zero_pack_kernel(
        int* __restrict__ cnt,
        const float* __restrict__ Wz, const float* __restrict__ Wr,
        const float* __restrict__ Wh,
        short* __restrict__ Bzr, short* __restrict__ Bh) {
    if (blockIdx.x < 49) {
        int i = blockIdx.x * 256 + threadIdx.x;   // < 12544 int4s
        ((int4*)cnt)[i] = make_int4(0, 0, 0, 0);
        return;
    }
    int gid = (blockIdx.x - 49) * 256 + threadIdx.x;   // < 6144
    if (gid < 4096) {                                   // zr: 64 (kt,ct) x 64 lanes
        int ktct = gid >> 6, lane = gid & 63;
        int kt = ktct >> 3, ct = ktct & 7;
        int colg = ct * 16 + (lane & 15);
        int k0 = kt * 32 + (lane >> 4) * 8;
        const float* W = (colg < 64) ? Wz : Wr;
        int c = colg & 63;
        short v[8];
        #pragma unroll
        for (int j = 0; j < 8; ++j) {
            int k = k0 + j;
            v[j] = f2bf(W[(k >> 7) * (128 * 64) + (k & 127) * 64 + c]);
        }
        *(bf16x8*)(Bzr + (size_t)ktct * 512 + lane * 8) = *(bf16x8*)v;
    } else {                                            // h: 32 (kt,ct) x 64 lanes
        int idx = gid - 4096;
        int ktct = idx >> 6, lane = idx & 63;
        int kt = ktct >> 2, ct = ktct & 3;
        int colg = ct * 16 + (lane & 15);
        int k0 = kt * 32 + (lane >> 4) * 8;
        short v[8];
        #pragma unroll
        for (int j = 0; j < 8; ++j) {
            int k = k0 + j;
            v[j] = f2bf(Wh[(k >> 7) * (128 * 64) + (k & 127) * 64 + colg]);
        }
        *(bf16x8*)(Bh + (size_t)ktct * 512 + lane * 8) = *(bf16x8*)v;
    }
}

// ======================= histogram (simple, 1 atomic/edge) =======================
// Round-6 lesson: fusing the fp32 deg atomic here doubled the atomic write
// streams -> ~50 MB writeback, 79 us. Keep ONE atomic array; deg comes from CSR.
__global__ void hist_kernel(const int* __restrict__ row, int* __restrict__ cnt) {
    int e = blockIdx.x * blockDim.x + threadIdx.x;
    if (e < N_EDGES) atomicAdd(&cnt[row[e]], 1);
}

// ======================= scan (cnt -> exclusive prefix = cursor) ==================
__global__ __launch_bounds__(256) void scan_part_kernel(const int* __restrict__ cnt,
                                                        int* __restrict__ part) {
    __shared__ int s[256];
    int t = threadIdx.x;
    s[t] = cnt[blockIdx.x * 256 + t];
    __syncthreads();
    for (int d = 128; d > 0; d >>= 1) {
        if (t < d) s[t] += s[t + d];
        __syncthreads();
    }
    if (t == 0) part[blockIdx.x] = s[0];
}

__global__ __launch_bounds__(256) void scan_root_kernel(const int* __restrict__ part,
                                                        int* __restrict__ poff) {
    __shared__ int s[256];
    int t = threadIdx.x;
    int v = (t < SCAN_BLOCKS) ? part[t] : 0;
    s[t] = v;
    __syncthreads();
    for (int d = 1; d < 256; d <<= 1) {
        int add = (t >= d) ? s[t - d] : 0;
        __syncthreads();
        s[t] += add;
        __syncthreads();
    }
    if (t < SCAN_BLOCKS) poff[t] = s[t] - v;
}

__global__ __launch_bounds__(256) void scan_add_kernel(const int* __restrict__ cnt,
                                                       const int* __restrict__ poff,
                                                       int* __restrict__ cursor) {
    __shared__ int s[256];
    int t = threadIdx.x;
    int i = blockIdx.x * 256 + t;
    int v = cnt[i];
    s[t] = v;
    __syncthreads();
    for (int d = 1; d < 256; d <<= 1) {
        int add = (t >= d) ? s[t - d] : 0;
        __syncthreads();
        s[t] += add;
        __syncthreads();
    }
    cursor[i] = s[t] - v + poff[blockIdx.x];
}

// ======================= XCD-partitioned scatter into CSR =========================
// KEPT from round 6 (it helped: 53 -> ~25 us). Each partition's ~800KB CSR slice
// is written by blocks on one XCD (via %8 round-robin) -> full-line coalescing.
// Partition predicate is consistent across blocks -> each edge done exactly once.
__global__ __launch_bounds__(256) void scatter_kernel(
        const int* __restrict__ row, const int* __restrict__ col,
        const float* __restrict__ w,
        int* __restrict__ cursor, int2* __restrict__ csr) {
    int part = blockIdx.x & 7;
    int chunk = blockIdx.x >> 3;
    int e0 = chunk * CHUNK_SZ;
    int e1 = min(e0 + CHUNK_SZ, N_EDGES);
    for (int e = e0 + (int)threadIdx.x; e < e1; e += 256) {
        int r = row[e];
        if (r / 6250 == part) {
            int pos = atomicAdd(&cursor[r], 1);
            csr[pos] = make_int2(col[e], __float_as_int(w[e]));
        }
    }
}

// deg from CSR ranges (sequential, no atomics); dinv = rsqrt(deg)
__global__ void degdinv_kernel(const int* __restrict__ cursor, const int2* __restrict__ csr,
                               float* __restrict__ dinv) {
    int n = blockIdx.x * blockDim.x + threadIdx.x;
    if (n >= N_NODES) return;
    int start = (n == 0) ? 0 : cursor[n - 1];
    int end = cursor[n];
    float d = 0.f;
    for (int e = start; e < end; ++e) d += __int_as_float(csr[e].y);
    dinv[n] = (d > 0.f) ? rsqrtf(d) : 0.f;
}

// xh[n*64+c] = (bf16(h*dinv) << 16) | bf16(x*dinv)
__global__ __launch_bounds__(256) void xh_pack_kernel(
        const float* __restrict__ x, const float* __restrict__ h,
        const float* __restrict__ dinv, unsigned* __restrict__ xh) {
    int i = blockIdx.x * 256 + threadIdx.x;   // exactly N*16 threads
    float d = dinv[i >> 4];
    float4 xv = ((const float4*)x)[i];
    float4 hv = ((const float4*)h)[i];
    uint4 o;
    o.x = ((unsigned)(unsigned short)f2bf(hv.x * d) << 16) | (unsigned short)f2bf(xv.x * d);
    o.y = ((unsigned)(unsigned short)f2bf(hv.y * d) << 16) | (unsigned short)f2bf(xv.y * d);
    o.z = ((unsigned)(unsigned short)f2bf(hv.z * d) << 16) | (unsigned short)f2bf(xv.z * d);
    o.w = ((unsigned)(unsigned short)f2bf(hv.w * d) << 16) | (unsigned short)f2bf(xv.w * d);
    ((uint4*)xh)[i] = o;
}

// ======================= propagation (pull, CSR) =======================
__global__ __launch_bounds__(256) void prop2_gather_kernel(
        const int* __restrict__ cursor, const int2* __restrict__ csr,
        const float* __restrict__ dinv, const unsigned* __restrict__ xh,
        float* __restrict__ Px, float* __restrict__ Ph) {
    int n = (blockIdx.x * 256 + threadIdx.x) >> 6;
    int lane = threadIdx.x & 63;
    if (n >= N_NODES) return;
    int start = (n == 0) ? 0 : cursor[n - 1];
    int end = cursor[n];
    float ax = 0.f, ah = 0.f;
    int e = start;
    for (; e + 4 <= end; e += 4) {
        int2 c0 = csr[e], c1 = csr[e + 1], c2 = csr[e + 2], c3 = csr[e + 3];
        unsigned v0 = xh[c0.x * C + lane];
        unsigned v1 = xh[c1.x * C + lane];
        unsigned v2 = xh[c2.x * C + lane];
        unsigned v3 = xh[c3.x * C + lane];
        float w0 = __int_as_float(c0.y), w1 = __int_as_float(c1.y);
        float w2 = __int_as_float(c2.y), w3 = __int_as_float(c3.y);
        ax = fmaf(w0, bf_lo(v0), ax);  ah = fmaf(w0, bf_hi(v0), ah);
        ax = fmaf(w1, bf_lo(v1), ax);  ah = fmaf(w1, bf_hi(v1), ah);
        ax = fmaf(w2, bf_lo(v2), ax);  ah = fmaf(w2, bf_hi(v2), ah);
        ax = fmaf(w3, bf_lo(v3), ax);  ah = fmaf(w3, bf_hi(v3), ah);
    }
    for (; e < end; ++e) {
        int2 cw = csr[e];
        unsigned v = xh[cw.x * C + lane];
        float wv = __int_as_float(cw.y);
        ax = fmaf(wv, bf_lo(v), ax);
        ah = fmaf(wv, bf_hi(v), ah);
    }
    float s = -dinv[n];
    Px[n * C + lane] = s * ax;
    Ph[n * C + lane] = s * ah;
}

__global__ __launch_bounds__(256) void prop1_gather_kernel(
        const int* __restrict__ cursor, const int2* __restrict__ csr,
        const float* __restrict__ dinv,
        const unsigned short* __restrict__ rhd, float* __restrict__ Prh) {
    int n = (blockIdx.x * 256 + threadIdx.x) >> 6;
    int lane = threadIdx.x & 63;
    if (n >= N_NODES) return;
    int start = (n == 0) ? 0 : cursor[n - 1];
    int end = cursor[n];
    float acc = 0.f;
    int e = start;
    for (; e + 4 <= end; e += 4) {
        int2 c0 = csr[e], c1 = csr[e + 1], c2 = csr[e + 2], c3 = csr[e + 3];
        float v0 = __uint_as_float((unsigned)rhd[c0.x * C + lane] << 16);
        float v1 = __uint_as_float((unsigned)rhd[c1.x * C + lane] << 16);
        float v2 = __uint_as_float((unsigned)rhd[c2.x * C + lane] << 16);
        float v3 = __uint_as_float((unsigned)rhd[c3.x * C + lane] << 16);
        acc = fmaf(__int_as_float(c0.y), v0, acc);
        acc = fmaf(__int_as_float(c1.y), v1, acc);
        acc = fmaf(__int_as_float(c2.y), v2, acc);
        acc = fmaf(__int_as_float(c3.y), v3, acc);
    }
    for (; e < end; ++e) {
        int2 cw = csr[e];
        float v = __uint_as_float((unsigned)rhd[cw.x * C + lane] << 16);
        acc = fmaf(__int_as_float(cw.y), v, acc);
    }
    Prh[n * C + lane] = -dinv[n] * acc;
}

// ======================= dense GEMMs (MFMA bf16) =======================
// One wave = 16 nodes x 128 cols (zr). A = [x|h|Px|Ph].
// A-frag: A[m=lane&15][k = kt*32 + (lane>>4)*8 + j].  C/D: col=lane&15, row=(lane>>4)*4+reg.
__global__ __launch_bounds__(256) void gemm_zr_mfma_kernel(
        const float* __restrict__ x,  const float* __restrict__ h,
        const float* __restrict__ Px, const float* __restrict__ Ph,
        const short* __restrict__ Bzr,
        const float* __restrict__ bz, const float* __restrict__ br,
        const float* __restrict__ dinv,
        float* __restrict__ z, float* __restrict__ rh, unsigned short* __restrict__ rhd) {
    int wave = (blockIdx.x * 256 + threadIdx.x) >> 6;
    int lane = threadIdx.x & 63;
    int node0 = wave * 16;
    if (node0 >= N_NODES) return;
    int rowA = lane & 15, q = lane >> 4;
    int nodeA = node0 + rowA;

    f32x4 acc[8];
    #pragma unroll
    for (int i = 0; i < 8; ++i) acc[i] = (f32x4){0.f, 0.f, 0.f, 0.f};

    const bf16x8* Bp = (const bf16x8*)Bzr;
    #pragma unroll
    for (int kt = 0; kt < 8; ++kt) {
        const float* src = (kt < 2) ? x : (kt < 4) ? h : (kt < 6) ? Px : Ph;
        const float* p = src + (size_t)nodeA * C + (kt & 1) * 32 + q * 8;
        float4 f0 = *(const float4*)p;
        float4 f1 = *(const float4*)(p + 4);
        short av[8] = {f2bf(f0.x), f2bf(f0.y), f2bf(f0.z), f2bf(f0.w),
                       f2bf(f1.x), f2bf(f1.y), f2bf(f1.z), f2bf(f1.w)};
        bf16x8 a = *(bf16x8*)av;
        #pragma unroll
        for (int ct = 0; ct < 8; ++ct) {
            bf16x8 b = Bp[(kt * 8 + ct) * 64 + lane];
            acc[ct] = __builtin_amdgcn_mfma_f32_16x16x32_bf16(a, b, acc[ct], 0, 0, 0);
        }
    }

    float dv[4];
    #pragma unroll
    for (int r = 0; r < 4; ++r) dv[r] = dinv[node0 + q * 4 + r];

    #pragma unroll
    for (int ct = 0; ct < 8; ++ct) {
        int colg = ct * 16 + (lane & 15);
        if (ct < 4) {                       // z columns
            float bias = bz[colg];
            #pragma unroll
            for (int r = 0; r < 4; ++r) {
                int node = node0 + q * 4 + r;
                z[(size_t)node * C + colg] = fast_sigmoid(acc[ct][r] + bias);
            }
        } else {                            // r columns -> rh (fp32), rhd (bf16)
            int oc = colg - 64;
            float bias = br[oc];
            #pragma unroll
            for (int r = 0; r < 4; ++r) {
                int node = node0 + q * 4 + r;
                float sg = fast_sigmoid(acc[ct][r] + bias);
                float rhv = sg * h[(size_t)node * C + oc];
                rh [(size_t)node * C + oc] = rhv;
                rhd[(size_t)node * C + oc] = (unsigned short)f2bf(rhv * dv[r]);
            }
        }
    }
}

// One wave = 16 nodes x 64 cols. A = [x|rh|Px|Prh]. out = (1-z)*h + z*tanh(pre)
__global__ __launch_bounds__(256) void gemm_h_mfma_kernel(
        const float* __restrict__ x,  const float* __restrict__ rh,
        const float* __restrict__ Px, const float* __restrict__ Prh,
        const short* __restrict__ Bh, const float* __restrict__ bh,
        const float* __restrict__ z,  const float* __restrict__ h,
        float* __restrict__ out) {
    int wave = (blockIdx.x * 256 + threadIdx.x) >> 6;
    int lane = threadIdx.x & 63;
    int node0 = wave * 16;
    if (node0 >= N_NODES) return;
    int rowA = lane & 15, q = lane >> 4;
    int nodeA = node0 + rowA;

    f32x4 acc[4];
    #pragma unroll
    for (int i = 0; i < 4; ++i) acc[i] = (f32x4){0.f, 0.f, 0.f, 0.f};

    const bf16x8* Bp = (const bf16x8*)Bh;
    #pragma unroll
    for (int kt = 0; kt < 8; ++kt) {
        const float* src = (kt < 2) ? x : (kt < 4) ? rh : (kt < 6) ? Px : Prh;
        const float* p = src + (size_t)nodeA * C + (kt & 1) * 32 + q * 8;
        float4 f0 = *(const float4*)p;
        float4 f1 = *(const float4*)(p + 4);
        short av[8] = {f2bf(f0.x), f2bf(f0.y), f2bf(f0.z), f2bf(f0.w),
                       f2bf(f1.x), f2bf(f1.y), f2bf(f1.z), f2bf(f1.w)};
        bf16x8 a = *(bf16x8*)av;
        #pragma unroll
        for (int ct = 0; ct < 4; ++ct) {
            bf16x8 b = Bp[(kt * 4 + ct) * 64 + lane];
            acc[ct] = __builtin_amdgcn_mfma_f32_16x16x32_bf16(a, b, acc[ct], 0, 0, 0);
        }
    }

    #pragma unroll
    for (int ct = 0; ct < 4; ++ct) {
        int oc = ct * 16 + (lane & 15);
        float bias = bh[oc];
        #pragma unroll
        for (int r = 0; r < 4; ++r) {
            int node = node0 + q * 4 + r;
            float ht = fast_tanh(acc[ct][r] + bias);
            float zz = z[(size_t)node * C + oc];
            float hv = h[(size_t)node * C + oc];
            out[(size_t)node * C + oc] = (1.f - zz) * hv + zz * ht;
        }
    }
}

extern "C" void kernel_launch(void* const* d_in, const int* in_sizes, int n_in,
                              void* d_out, int out_size, void* d_ws, size_t ws_size,
                              hipStream_t stream) {
    const float* x    = (const float*)d_in[0];
    const int*   eidx = (const int*)  d_in[1];
    const float* w    = (const float*)d_in[2];
    const float* h    = (const float*)d_in[3];
    const float* Wz   = (const float*)d_in[4];
    const float* bz   = (const float*)d_in[5];
    const float* Wr   = (const float*)d_in[6];
    const float* br   = (const float*)d_in[7];
    const float* Wh   = (const float*)d_in[8];
    const float* bh   = (const float*)d_in[9];
    float* out = (float*)d_out;
    float* ws  = (float*)d_ws;

    const int* row = eidx;
    const int* col = eidx + N_EDGES;

    int*            cnt  = (int*)(ws + OFF_CNT);      // becomes cursor / rowptr+1
    int*            part = (int*)(ws + OFF_PART);
    int*            poff = (int*)(ws + OFF_POFF);
    float*          dinv = ws + OFF_DINV;
    int2*           csr  = (int2*)(ws + OFF_CSR);
    short*          Bzr  = (short*)(ws + OFF_BZR);
    short*          Bh   = (short*)(ws + OFF_BH);
    float*          Px   = ws + OFF_PX;
    float*          Ph   = ws + OFF_PH;               // later Prh
    unsigned*       xh   = (unsigned*)(ws + OFF_XH);
    float*          rh   = ws + OFF_RH;
    unsigned short* rhd  = (unsigned short*)(ws + OFF_RHD);
    float*          z    = out;                       // z lives in d_out until gemm_h

    // ---- zero cnt, pack weights (fused) ----
    zero_pack_kernel<<<49 + 24, 256, 0, stream>>>(cnt, Wz, Wr, Wh, Bzr, Bh);

    // ---- histogram (simple) ----
    hist_kernel<<<(N_EDGES + 255) / 256, 256, 0, stream>>>(row, cnt);

    // ---- exclusive scan -> cursor ----
    scan_part_kernel<<<SCAN_BLOCKS, 256, 0, stream>>>(cnt, part);
    scan_root_kernel<<<1, 256, 0, stream>>>(part, poff);
    scan_add_kernel<<<SCAN_BLOCKS, 256, 0, stream>>>(cnt, poff, cnt);

    // ---- scatter into CSR (XCD-partitioned, kept from round 6) ----
    scatter_kernel<<<8 * HIST_CHUNKS, 256, 0, stream>>>(row, col, w, cnt, csr);

    // ---- deg/dinv from CSR ----
    degdinv_kernel<<<(N_NODES + 255) / 256, 256, 0, stream>>>(cnt, csr, dinv);

    // ---- packed bf16 features ----
    xh_pack_kernel<<<(N_NODES * 16) / 256, 256, 0, stream>>>(x, h, dinv, xh);

    // ---- Px = Lhat@x, Ph = Lhat@h ----
    prop2_gather_kernel<<<(N_NODES * 64 + 255) / 256, 256, 0, stream>>>(
        cnt, csr, dinv, xh, Px, Ph);

    // ---- z, rh, rhd ----
    {
        int waves = (N_NODES + 15) / 16;          // 3125
        int blocks = (waves + 3) / 4;             // 782
        gemm_zr_mfma_kernel<<<blocks, 256, 0, stream>>>(
            x, h, Px, Ph, Bzr, bz, br, dinv, z, rh, rhd);
    }

    // ---- Prh = Lhat@(r*h) (into Ph slot) ----
    prop1_gather_kernel<<<(N_NODES * 64 + 255) / 256, 256, 0, stream>>>(
        cnt, csr, dinv, rhd, Ph);

    // ---- candidate + GRU blend ----
    {
        int waves = (N_NODES + 15) / 16;
        int blocks = (waves + 3) / 4;
        gemm_h_mfma_kernel<<<blocks, 256, 0, stream>>>(
            x, rh, Px, Ph, Bh, bh, z, h, out);
    }
}